// Round 2
// baseline (147.980 us; speedup 1.0000x reference)
//
#include <hip/hip_runtime.h>

// B=2, S=2048, D_IN=1024, H=16, HD=64 causal MHA. fp32 I/O, bf16 MFMA inside.
// prep_k (x->bf16 + W->Wt[mat,h,e,d] merged) ;
// proj_k (fused QKV GEMM, 128x192 tile, DOUBLE-BUFFERED XOR-swizzled LDS
//   staging via global_load_lds; Q pre-scaled 1/8*log2e; V stored ^T) ;
// attn_k (r10: 32x32 MFMA, in-register P via PKHI+permlane32_swap. 256 blocks
//   = 1/CU, 4 waves, VGPR budget 256 (no spill). Each block runs q-tiles
//   (p, 15-p) SEQUENTIALLY -> exactly 17 iters/block, balance independent of
//   scheduler. XCD swizzle pins each bh's 8 blocks to one XCD -> K/V L2-hot).

#define DI   1024
#define HD   64
#define NH   16
#define SEQ  2048
#define NB   2

typedef unsigned short u16;
typedef unsigned short us8 __attribute__((ext_vector_type(8)));
typedef unsigned short us4 __attribute__((ext_vector_type(4)));
typedef unsigned int   u32x2 __attribute__((ext_vector_type(2)));
typedef short bf8 __attribute__((ext_vector_type(8)));   // 8 x bf16
typedef float f4 __attribute__((ext_vector_type(4)));
typedef float f16v __attribute__((ext_vector_type(16)));

#define MFMA16(a, b, c) __builtin_amdgcn_mfma_f32_16x16x32_bf16((a), (b), (c), 0, 0, 0)
#define MFMA32(a, b, c) __builtin_amdgcn_mfma_f32_32x32x16_bf16((a), (b), (c), 0, 0, 0)

#if __has_builtin(__builtin_amdgcn_exp2f)
#define EXP2(x) __builtin_amdgcn_exp2f(x)
#else
#define EXP2(x) exp2f(x)
#endif

#if __has_builtin(__builtin_amdgcn_perm)
#define PKHI(a, b) __builtin_amdgcn_perm((a), (b), 0x07060302u)
#else
__device__ __forceinline__ unsigned PKHI(unsigned a, unsigned b) {
  return (b >> 16) | (a & 0xffff0000u);
}
#endif

__device__ __forceinline__ u16 f2bf(float f) {  // RNE fp32 -> bf16
  unsigned u = __float_as_uint(f);
  u += 0x7fffu + ((u >> 16) & 1u);
  return (u16)(u >> 16);
}

// async global->LDS, 16B/lane; LDS dest = wave-uniform base + lane*16.
__device__ __forceinline__ void async16(const u16* g, u16* l) {
  __builtin_amdgcn_global_load_lds((const __attribute__((address_space(1))) void*)g,
                                   (__attribute__((address_space(3))) void*)l,
                                   16, 0, 0);
}

// ------------- prep: x fp32->bf16 (grid.x<2048) + W transpose (>=2048) -----
__global__ __launch_bounds__(256) void prep_k(const float* __restrict__ x,
                                              const float* __restrict__ Wq,
                                              const float* __restrict__ Wk,
                                              const float* __restrict__ Wv,
                                              u16* __restrict__ xb,
                                              u16* __restrict__ Wt) {
  __shared__ __align__(16) u16 tile[64][72];
  const int bid = blockIdx.x;
  if (bid < 2048) {                              // ---- x conversion ----
    const int i = (bid * 256 + threadIdx.x) * 8;
    float4 v0 = *(const float4*)(x + i);
    float4 v1 = *(const float4*)(x + i + 4);
    us8 o;
    o[0] = f2bf(v0.x); o[1] = f2bf(v0.y); o[2] = f2bf(v0.z); o[3] = f2bf(v0.w);
    o[4] = f2bf(v1.x); o[5] = f2bf(v1.y); o[6] = f2bf(v1.z); o[7] = f2bf(v1.w);
    *(us8*)(xb + i) = o;
    return;
  }
  const int idx = bid - 2048;                    // ---- W transpose ----
  const int mh = idx >> 4;                       // mat*16 + h, 0..47
  const int d0 = (idx & 15) * 64;
  const int mat = mh >> 4, h = mh & 15;
  const float* W = (mat == 0 ? Wq : (mat == 1 ? Wk : Wv)) + (size_t)h * DI * HD;
  const int t = threadIdx.x;
  {
    const int r = t >> 2, c = (t & 3) * 16;
    const float* src = W + (size_t)(d0 + r) * HD + c;
    #pragma unroll
    for (int j = 0; j < 4; j++) {
      float4 v = *(const float4*)(src + j * 4);
      tile[r][c + j * 4 + 0] = f2bf(v.x);
      tile[r][c + j * 4 + 1] = f2bf(v.y);
      tile[r][c + j * 4 + 2] = f2bf(v.z);
      tile[r][c + j * 4 + 3] = f2bf(v.w);
    }
  }
  __syncthreads();
  {
    const int e = t >> 2, c = (t & 3) * 16;
    __align__(16) u16 tmp[16];
    #pragma unroll
    for (int i = 0; i < 16; i++) tmp[i] = tile[c + i][e];
    u16* dst = Wt + ((size_t)mh * HD + e) * DI + d0 + c;
    *(us8*)dst       = *(us8*)&tmp[0];
    *(us8*)(dst + 8) = *(us8*)&tmp[8];
  }
}

// ---------------- fused QKV GEMM: [4096x1024] x [1024x3072] ----------------
// 128x192 tile, grid (32,16) = 512 blocks = 2/CU. 4 waves: wave (wm,wn) owns
// 64x96. BK=64. Double-buffered XOR-swizzled LDS (80 KB), prefetch issued
// after the barrier so global latency overlaps compute (r8-attn pattern).
__global__ __launch_bounds__(256, 2) void proj_k(const u16* __restrict__ x,
                                                 const u16* __restrict__ Wt,
                                                 u16* __restrict__ Qo,
                                                 u16* __restrict__ Ko,
                                                 u16* __restrict__ Vo) {
  __shared__ __align__(16) u16 smem[40960];      // xs 2x8192 | ws 2x12288
  u16* const xs = smem;                          // +cb 0/8192
  u16* const ws = smem + 16384;                  // +cb 0/12288
  const int m0 = blockIdx.x * 128, n0 = blockIdx.y * 192;
  const int tid = threadIdx.x, w = tid >> 6, lane = tid & 63;
  const int l15 = lane & 15, quad = lane >> 4, l7 = l15 & 7;
  const int lrow = lane >> 3, lch = lane & 7;
  const int wm = w >> 1, wn = w & 1;

  f4 acc[4][6];
  #pragma unroll
  for (int i = 0; i < 4; i++)
    #pragma unroll
    for (int j = 0; j < 6; j++) {
      f4 z = {0.f, 0.f, 0.f, 0.f};
      acc[i][j] = z;
    }

  const u16* xg = x  + (size_t)(m0 + lrow) * DI + ((lch ^ lrow) * 8);
  const u16* wg = Wt + (size_t)(n0 + lrow) * DI + ((lch ^ lrow) * 8);

  // prologue: stage k0=0 into buffer 0
  #pragma unroll
  for (int i = 0; i < 4; i++)
    async16(xg + (size_t)(i * 32 + w * 8) * DI, &xs[(i * 32 + w * 8) * 64]);
  #pragma unroll
  for (int c = 0; c < 6; c++)
    async16(wg + (size_t)(w * 48 + c * 8) * DI, &ws[(w * 48 + c * 8) * 64]);

  for (int it = 0; it < 16; it++) {
    const int cbx = (it & 1) * 8192, cbw = (it & 1) * 12288;
    __syncthreads();                             // drains this iter's loads
    if (it + 1 < 16) {                           // prefetch next k-tile
      const int k1 = (it + 1) * 64;
      const int nbx = 8192 - cbx, nbw = 12288 - cbw;
      #pragma unroll
      for (int i = 0; i < 4; i++)
        async16(xg + (size_t)(i * 32 + w * 8) * DI + k1,
                &xs[nbx + (i * 32 + w * 8) * 64]);
      #pragma unroll
      for (int c = 0; c < 6; c++)
        async16(wg + (size_t)(w * 48 + c * 8) * DI + k1,
                &ws[nbw + (w * 48 + c * 8) * 64]);
    }
    #pragma unroll
    for (int ks = 0; ks < 64; ks += 32) {
      const int c0 = (ks >> 3) + quad;
      bf8 af[4], bfr[6];
      #pragma unroll
      for (int i = 0; i < 4; i++)
        af[i] = *(const bf8*)&xs[cbx + (wm * 64 + i * 16 + l15) * 64 + ((c0 ^ l7) * 8)];
      #pragma unroll
      for (int i = 0; i < 6; i++)
        bfr[i] = *(const bf8*)&ws[cbw + (wn * 96 + i * 16 + l15) * 64 + ((c0 ^ l7) * 8)];
      #pragma unroll
      for (int mi = 0; mi < 4; mi++)
        #pragma unroll
        for (int ni = 0; ni < 6; ni++)
          acc[mi][ni] = MFMA16(af[mi], bfr[ni], acc[mi][ni]);
    }
  }

  const float qscale = 0.125f * 1.44269504088896340736f;
  #pragma unroll
  for (int mi = 0; mi < 4; mi++) {
    const int mrow = m0 + wm * 64 + mi * 16 + quad * 4;
    const int b = mrow >> 11, sb = mrow & (SEQ - 1);
    #pragma unroll
    for (int ni = 0; ni < 6; ni++) {
      const int nf = n0 + wn * 96 + ni * 16;     // 0..3071
      const int mat = nf >> 10;
      const int h = (nf >> 6) & 15;
      const int e = (nf & 63) + l15;
      if (mat == 2) {
        __align__(8) u16 pk[4];
        #pragma unroll
        for (int r = 0; r < 4; r++) pk[r] = f2bf(acc[mi][ni][r]);
        *(us4*)(Vo + (((size_t)b * NH + h) * HD + e) * SEQ + sb) = *(us4*)pk;
      } else {
        u16* O = mat ? Ko : Qo;
        const float sc = mat ? 1.0f : qscale;
        #pragma unroll
        for (int r = 0; r < 4; r++)
          O[(((size_t)b * NH + h) * SEQ + sb + r) * HD + e] = f2bf(acc[mi][ni][r] * sc);
      }
    }
  }
}

// ------- flash attention r10: 1 block/CU, sequential paired tiles ----------
// Wave w owns q rows [t*128 + w*32, +32). S^T = K·Q^T per mf (32 keys):
// lane holds P[key][q=l31]; PKHI-pack + 4x v_permlane32_swap_b32 rebuild the
// PV A-operand (P^T) frags in-register. O = P^T x V^T -> C[q][d], col=lane=d
// => coalesced fp32 stores. LDS: Ks 2x128x64 (chunk^(key&7)), Vs 2x64x128
// (chunk^(d&15)), both conflict-free under the b128 read patterns.
// Grid (8,32): XCD = linear%8 = blockIdx.x, so bh = x*4+(y&3) pins each bh's
// 8 blocks to one XCD (K/V 2MB/XCD -> L2-hot). Block runs tiles p and 15-p
// SEQUENTIALLY: always 17 iters/block -> perfect balance at 1 block/CU, and
// launch_bounds(256,1) gives a 256-VGPR budget (no spills).
__global__ __launch_bounds__(256, 1) void attn_k(const u16* __restrict__ Qo,
                                                 const u16* __restrict__ Ko,
                                                 const u16* __restrict__ Vo,
                                                 float* __restrict__ out) {
  __shared__ __align__(16) u16 Ks[2 * 128 * 64];   // [buf][key][d]
  __shared__ __align__(16) u16 Vs[2 * 64 * 128];   // [buf][d][key]
  __shared__ float Ls[128];
  const int p  = blockIdx.y >> 2;                  // pair index 0..7
  const int bh = (blockIdx.x << 2) | (blockIdx.y & 3);
  const int b = bh >> 4, h = bh & 15;
  const int tid = threadIdx.x, w = tid >> 6, lane = tid & 63;
  const int l31 = lane & 31, hi = lane >> 5;
  const int k7 = l31 & 7, v15 = l31 & 15;

  const u16* Qb = Qo + (size_t)bh * SEQ * HD;
  const u16* Kb = Ko + (size_t)bh * SEQ * HD;
  const u16* Vb = Vo + (size_t)bh * HD * SEQ;

  const int kl = lane >> 3, kc = lane & 7;         // K staging lane decomp
  const int vl = lane >> 4, vc = lane & 15;        // V staging lane decomp
  const int mq = w * 32 + l31;                     // lane's q row within tile

  #pragma unroll 1
  for (int half = 0; half < 2; ++half) {
    const int t = half ? (15 - p) : p;             // tiles p then 15-p
    const int nI = t + 1;

    // Q B-operand frags [16d x 32q]: lane(q=l31,hi): d = ks*16 + hi*8 .. +8
    bf8 bq[4];
    #pragma unroll
    for (int ks = 0; ks < 4; ks++)
      bq[ks] = *(const bf8*)(Qb + (size_t)(t * 128 + w * 32 + l31) * HD + ks * 16 + hi * 8);

    f16v o0, o1, zf;
    #pragma unroll
    for (int i = 0; i < 16; i++) { o0[i] = 0.f; o1[i] = 0.f; zf[i] = 0.f; }
    float lsum = 0.f;

    const u16* kg = Kb + (size_t)(w * 32 + kl) * HD + ((kc ^ kl) * 8);
    const u16* vg[4];
    u16* ldsK[4];
    u16* ldsV[4];
    #pragma unroll
    for (int i = 0; i < 4; i++) {
      const int vr = w * 16 + i * 4;
      const int f = (i * 4 + vl) & 15;
      vg[i] = Vb + (size_t)(vr + vl) * SEQ + ((vc ^ f) * 8);
      ldsK[i] = &Ks[(w * 32 + i * 8) * 64];
      ldsV[i] = &Vs[vr * 128];
    }

    #pragma unroll
    for (int i = 0; i < 4; i++) {
      async16(kg + i * 512, ldsK[i]);
      async16(vg[i], ldsV[i]);
    }
    kg += 128 * HD;
    #pragma unroll
    for (int i = 0; i < 4; i++) vg[i] += 128;

    for (int it = 0; it < nI; ++it) {
      const int cb = (it & 1) * 8192;
      __syncthreads();
      if (it + 1 < nI) {
        const int nb = 8192 - cb;
        #pragma unroll
        for (int i = 0; i < 4; i++) {
          async16(kg + i * 512, ldsK[i] + nb);
          async16(vg[i], ldsV[i] + nb);
        }
        kg += 128 * HD;
        #pragma unroll
        for (int i = 0; i < 4; i++) vg[i] += 128;
      }
      const bool domask = (it == nI - 1);

      #pragma unroll
      for (int mf = 0; mf < 4; mf++) {
        // ---- QK^T: S^T[32k x 32q], accumulate over 4 k-steps of d ----
        f16v s;
        __builtin_amdgcn_s_setprio(1);
        {
          bf8 ak = *(const bf8*)&Ks[cb + mf * 2048 + l31 * 64 + ((hi ^ k7) * 8)];
          s = MFMA32(ak, bq[0], zf);
        }
        #pragma unroll
        for (int ks = 1; ks < 4; ks++) {
          bf8 ak = *(const bf8*)&Ks[cb + mf * 2048 + l31 * 64 + (((2 * ks + hi) ^ k7) * 8)];
          s = MFMA32(ak, bq[ks], s);
        }
        __builtin_amdgcn_s_setprio(0);

        // ---- exp2 + mask + running row-sum (q = l31) ----
        unsigned pu[16];
        #pragma unroll
        for (int r = 0; r < 16; r++) {
          float pv = EXP2(s[r]);
          if (domask) {
            const int kt = mf * 32 + (r & 3) + 8 * (r >> 2) + 4 * hi;
            pv = (kt <= mq) ? pv : 0.f;
          }
          lsum += pv;
          pu[r] = __float_as_uint(pv);
        }
        // ---- pack pairs to bf16, half-wave swap -> PV A-operand frags ----
        unsigned a0 = PKHI(pu[1],  pu[0]),  a1 = PKHI(pu[3],  pu[2]);
        unsigned a2 = PKHI(pu[5],  pu[4]),  a3 = PKHI(pu[7],  pu[6]);
        unsigned a4 = PKHI(pu[9],  pu[8]),  a5 = PKHI(pu[11], pu[10]);
        unsigned a6 = PKHI(pu[13], pu[12]), a7 = PKHI(pu[15], pu[14]);
        asm("v_permlane32_swap_b32 %0, %1" : "+v"(a0), "+v"(a2));
        asm("v_permlane32_swap_b32 %0, %1" : "+v"(a1), "+v"(a3));
        asm("v_permlane32_swap_b32 %0, %1" : "+v"(a4), "+v"(a6));
        asm("v_permlane32_swap_b32 %0, %1" : "+v"(a5), "+v"(a7));
        bf8 pf0, pf1;
        ((unsigned*)&pf0)[0] = a0; ((unsigned*)&pf0)[1] = a1;
        ((unsigned*)&pf0)[2] = a2; ((unsigned*)&pf0)[3] = a3;
        ((unsigned*)&pf1)[0] = a4; ((unsigned*)&pf1)[1] = a5;
        ((unsigned*)&pf1)[2] = a6; ((unsigned*)&pf1)[3] = a7;

        // ---- PV: O[q][d] += P^T-frag x V^T-frag, k-slots 2mf, 2mf+1 ----
        __builtin_amdgcn_s_setprio(1);
        {
          const int c0 = ((4 * mf + hi) ^ v15) * 8;
          bf8 vf0 = *(const bf8*)&Vs[cb + l31 * 128 + c0];
          bf8 vf1 = *(const bf8*)&Vs[cb + 4096 + l31 * 128 + c0];
          o0 = MFMA32(pf0, vf0, o0);
          o1 = MFMA32(pf0, vf1, o1);
        }
        {
          const int c1 = ((4 * mf + 2 + hi) ^ v15) * 8;
          bf8 vf0 = *(const bf8*)&Vs[cb + l31 * 128 + c1];
          bf8 vf1 = *(const bf8*)&Vs[cb + 4096 + l31 * 128 + c1];
          o0 = MFMA32(pf1, vf0, o0);
          o1 = MFMA32(pf1, vf1, o1);
        }
        __builtin_amdgcn_s_setprio(0);
      }
    }

    // ---- epilogue: l across half-waves, broadcast via LDS, scaled store ----
    const float lt = lsum + __shfl_xor(lsum, 32, 64);
    if (hi == 0) Ls[w * 32 + l31] = lt;
    __syncthreads();   // also fences all LDS reads before next half's staging

    float* op = out + ((size_t)(b * SEQ + t * 128 + w * 32)) * (NH * HD) + h * HD + l31;
    #pragma unroll
    for (int r = 0; r < 16; r++) {
      const int qr = (r & 3) + 8 * (r >> 2) + 4 * hi;
      const float linv = 1.0f / Ls[w * 32 + qr];
      op[(size_t)qr * (NH * HD)]      = o0[r] * linv;
      op[(size_t)qr * (NH * HD) + 32] = o1[r] * linv;
    }
  }
}

extern "C" void kernel_launch(void* const* d_in, const int* in_sizes, int n_in,
                              void* d_out, int out_size, void* d_ws, size_t ws_size,
                              hipStream_t stream) {
  const float* x  = (const float*)d_in[0];
  const float* Wq = (const float*)d_in[1];
  const float* Wk = (const float*)d_in[2];
  const float* Wv = (const float*)d_in[3];
  float* out = (float*)d_out;

  u16* xb = (u16*)d_ws;
  u16* Wt = xb + (size_t)NB * SEQ * DI;
  u16* Qo = Wt + (size_t)3 * NH * HD * DI;
  u16* Ko = Qo + (size_t)NB * NH * SEQ * HD;
  u16* Vo = Ko + (size_t)NB * NH * SEQ * HD;

  prep_k<<<dim3(2048 + 768), 256, 0, stream>>>(x, Wq, Wk, Wv, xb, Wt);
  proj_k<<<dim3(32, 16), 256, 0, stream>>>(xb, Wt, Qo, Ko, Vo);
  attn_k<<<dim3(8, 32), 256, 0, stream>>>(Qo, Ko, Vo, out);
}

// Round 3
// 139.220 us; speedup vs baseline: 1.0629x; 1.0629x over previous
//
#include <hip/hip_runtime.h>

// B=2, S=2048, D_IN=1024, H=16, HD=64 causal MHA. fp32 I/O, bf16 MFMA inside.
// prep_k (x->bf16 + W->Wt[mat,h,e,d] merged) ;
// proj_k (fused QKV GEMM, 128x192 tile, DOUBLE-BUFFERED XOR-swizzled LDS
//   staging via global_load_lds; Q pre-scaled 1/8*log2e; V stored ^T) ;
// attn_k (r11: r10 inner loop unchanged; grid (32,16) = 512 blocks = 2/CU
//   -> 2 waves/SIMD (r10's 1 wave/SIMD was stall-bound at Occ 9.7%).
//   XCD = bh%8 keeps K/V L2-pinned (12MB fetch, r10-verified). Tile remap
//   t = y<8 ? y : 23-y pairs complementary (t,15-t) on co-resident blocks).

#define DI   1024
#define HD   64
#define NH   16
#define SEQ  2048
#define NB   2

typedef unsigned short u16;
typedef unsigned short us8 __attribute__((ext_vector_type(8)));
typedef unsigned short us4 __attribute__((ext_vector_type(4)));
typedef unsigned int   u32x2 __attribute__((ext_vector_type(2)));
typedef short bf8 __attribute__((ext_vector_type(8)));   // 8 x bf16
typedef float f4 __attribute__((ext_vector_type(4)));
typedef float f16v __attribute__((ext_vector_type(16)));

#define MFMA16(a, b, c) __builtin_amdgcn_mfma_f32_16x16x32_bf16((a), (b), (c), 0, 0, 0)
#define MFMA32(a, b, c) __builtin_amdgcn_mfma_f32_32x32x16_bf16((a), (b), (c), 0, 0, 0)

#if __has_builtin(__builtin_amdgcn_exp2f)
#define EXP2(x) __builtin_amdgcn_exp2f(x)
#else
#define EXP2(x) exp2f(x)
#endif

#if __has_builtin(__builtin_amdgcn_perm)
#define PKHI(a, b) __builtin_amdgcn_perm((a), (b), 0x07060302u)
#else
__device__ __forceinline__ unsigned PKHI(unsigned a, unsigned b) {
  return (b >> 16) | (a & 0xffff0000u);
}
#endif

__device__ __forceinline__ u16 f2bf(float f) {  // RNE fp32 -> bf16
  unsigned u = __float_as_uint(f);
  u += 0x7fffu + ((u >> 16) & 1u);
  return (u16)(u >> 16);
}

// async global->LDS, 16B/lane; LDS dest = wave-uniform base + lane*16.
__device__ __forceinline__ void async16(const u16* g, u16* l) {
  __builtin_amdgcn_global_load_lds((const __attribute__((address_space(1))) void*)g,
                                   (__attribute__((address_space(3))) void*)l,
                                   16, 0, 0);
}

// ------------- prep: x fp32->bf16 (grid.x<2048) + W transpose (>=2048) -----
__global__ __launch_bounds__(256) void prep_k(const float* __restrict__ x,
                                              const float* __restrict__ Wq,
                                              const float* __restrict__ Wk,
                                              const float* __restrict__ Wv,
                                              u16* __restrict__ xb,
                                              u16* __restrict__ Wt) {
  __shared__ __align__(16) u16 tile[64][72];
  const int bid = blockIdx.x;
  if (bid < 2048) {                              // ---- x conversion ----
    const int i = (bid * 256 + threadIdx.x) * 8;
    float4 v0 = *(const float4*)(x + i);
    float4 v1 = *(const float4*)(x + i + 4);
    us8 o;
    o[0] = f2bf(v0.x); o[1] = f2bf(v0.y); o[2] = f2bf(v0.z); o[3] = f2bf(v0.w);
    o[4] = f2bf(v1.x); o[5] = f2bf(v1.y); o[6] = f2bf(v1.z); o[7] = f2bf(v1.w);
    *(us8*)(xb + i) = o;
    return;
  }
  const int idx = bid - 2048;                    // ---- W transpose ----
  const int mh = idx >> 4;                       // mat*16 + h, 0..47
  const int d0 = (idx & 15) * 64;
  const int mat = mh >> 4, h = mh & 15;
  const float* W = (mat == 0 ? Wq : (mat == 1 ? Wk : Wv)) + (size_t)h * DI * HD;
  const int t = threadIdx.x;
  {
    const int r = t >> 2, c = (t & 3) * 16;
    const float* src = W + (size_t)(d0 + r) * HD + c;
    #pragma unroll
    for (int j = 0; j < 4; j++) {
      float4 v = *(const float4*)(src + j * 4);
      tile[r][c + j * 4 + 0] = f2bf(v.x);
      tile[r][c + j * 4 + 1] = f2bf(v.y);
      tile[r][c + j * 4 + 2] = f2bf(v.z);
      tile[r][c + j * 4 + 3] = f2bf(v.w);
    }
  }
  __syncthreads();
  {
    const int e = t >> 2, c = (t & 3) * 16;
    __align__(16) u16 tmp[16];
    #pragma unroll
    for (int i = 0; i < 16; i++) tmp[i] = tile[c + i][e];
    u16* dst = Wt + ((size_t)mh * HD + e) * DI + d0 + c;
    *(us8*)dst       = *(us8*)&tmp[0];
    *(us8*)(dst + 8) = *(us8*)&tmp[8];
  }
}

// ---------------- fused QKV GEMM: [4096x1024] x [1024x3072] ----------------
// 128x192 tile, grid (32,16) = 512 blocks = 2/CU. 4 waves: wave (wm,wn) owns
// 64x96. BK=64. Double-buffered XOR-swizzled LDS (80 KB), prefetch issued
// after the barrier so global latency overlaps compute (T3 recipe placement).
__global__ __launch_bounds__(256, 2) void proj_k(const u16* __restrict__ x,
                                                 const u16* __restrict__ Wt,
                                                 u16* __restrict__ Qo,
                                                 u16* __restrict__ Ko,
                                                 u16* __restrict__ Vo) {
  __shared__ __align__(16) u16 smem[40960];      // xs 2x8192 | ws 2x12288
  u16* const xs = smem;                          // +cb 0/8192
  u16* const ws = smem + 16384;                  // +cb 0/12288
  const int m0 = blockIdx.x * 128, n0 = blockIdx.y * 192;
  const int tid = threadIdx.x, w = tid >> 6, lane = tid & 63;
  const int l15 = lane & 15, quad = lane >> 4, l7 = l15 & 7;
  const int lrow = lane >> 3, lch = lane & 7;
  const int wm = w >> 1, wn = w & 1;

  f4 acc[4][6];
  #pragma unroll
  for (int i = 0; i < 4; i++)
    #pragma unroll
    for (int j = 0; j < 6; j++) {
      f4 z = {0.f, 0.f, 0.f, 0.f};
      acc[i][j] = z;
    }

  const u16* xg = x  + (size_t)(m0 + lrow) * DI + ((lch ^ lrow) * 8);
  const u16* wg = Wt + (size_t)(n0 + lrow) * DI + ((lch ^ lrow) * 8);

  // prologue: stage k0=0 into buffer 0
  #pragma unroll
  for (int i = 0; i < 4; i++)
    async16(xg + (size_t)(i * 32 + w * 8) * DI, &xs[(i * 32 + w * 8) * 64]);
  #pragma unroll
  for (int c = 0; c < 6; c++)
    async16(wg + (size_t)(w * 48 + c * 8) * DI, &ws[(w * 48 + c * 8) * 64]);

  for (int it = 0; it < 16; it++) {
    const int cbx = (it & 1) * 8192, cbw = (it & 1) * 12288;
    __syncthreads();                             // drains this iter's loads
    if (it + 1 < 16) {                           // prefetch next k-tile
      const int k1 = (it + 1) * 64;
      const int nbx = 8192 - cbx, nbw = 12288 - cbw;
      #pragma unroll
      for (int i = 0; i < 4; i++)
        async16(xg + (size_t)(i * 32 + w * 8) * DI + k1,
                &xs[nbx + (i * 32 + w * 8) * 64]);
      #pragma unroll
      for (int c = 0; c < 6; c++)
        async16(wg + (size_t)(w * 48 + c * 8) * DI + k1,
                &ws[nbw + (w * 48 + c * 8) * 64]);
    }
    #pragma unroll
    for (int ks = 0; ks < 64; ks += 32) {
      const int c0 = (ks >> 3) + quad;
      bf8 af[4], bfr[6];
      #pragma unroll
      for (int i = 0; i < 4; i++)
        af[i] = *(const bf8*)&xs[cbx + (wm * 64 + i * 16 + l15) * 64 + ((c0 ^ l7) * 8)];
      #pragma unroll
      for (int i = 0; i < 6; i++)
        bfr[i] = *(const bf8*)&ws[cbw + (wn * 96 + i * 16 + l15) * 64 + ((c0 ^ l7) * 8)];
      #pragma unroll
      for (int mi = 0; mi < 4; mi++)
        #pragma unroll
        for (int ni = 0; ni < 6; ni++)
          acc[mi][ni] = MFMA16(af[mi], bfr[ni], acc[mi][ni]);
    }
  }

  const float qscale = 0.125f * 1.44269504088896340736f;
  #pragma unroll
  for (int mi = 0; mi < 4; mi++) {
    const int mrow = m0 + wm * 64 + mi * 16 + quad * 4;
    const int b = mrow >> 11, sb = mrow & (SEQ - 1);
    #pragma unroll
    for (int ni = 0; ni < 6; ni++) {
      const int nf = n0 + wn * 96 + ni * 16;     // 0..3071
      const int mat = nf >> 10;
      const int h = (nf >> 6) & 15;
      const int e = (nf & 63) + l15;
      if (mat == 2) {
        __align__(8) u16 pk[4];
        #pragma unroll
        for (int r = 0; r < 4; r++) pk[r] = f2bf(acc[mi][ni][r]);
        *(us4*)(Vo + (((size_t)b * NH + h) * HD + e) * SEQ + sb) = *(us4*)pk;
      } else {
        u16* O = mat ? Ko : Qo;
        const float sc = mat ? 1.0f : qscale;
        #pragma unroll
        for (int r = 0; r < 4; r++)
          O[(((size_t)b * NH + h) * SEQ + sb + r) * HD + e] = f2bf(acc[mi][ni][r] * sc);
      }
    }
  }
}

// ------- flash attention r11: 2 blocks/CU, XCD-pinned, paired tiles --------
// Inner loop identical to r10 (verified). Grid (32,16): x = bh (XCD = bh%8
// -> each XCD serves 4 bh, K/V 2MB L2-resident, r10-measured 12MB fetch);
// y -> tile via t = y<8 ? y : 23-y so within-XCD blocks j and j+32 (likely
// CU co-residents) carry complementary (t, 15-t) -> ~17 iters per CU.
// 2 blocks/CU x 4 waves = 2 waves/SIMD (r10's 1 wave/SIMD was stall-bound).
__global__ __launch_bounds__(256, 2) void attn_k(const u16* __restrict__ Qo,
                                                 const u16* __restrict__ Ko,
                                                 const u16* __restrict__ Vo,
                                                 float* __restrict__ out) {
  __shared__ __align__(16) u16 Ks[2 * 128 * 64];   // [buf][key][d]
  __shared__ __align__(16) u16 Vs[2 * 64 * 128];   // [buf][d][key]
  __shared__ float Ls[128];
  const int bh = blockIdx.x;                       // XCD = bh % 8
  const int y  = blockIdx.y;
  const int t  = (y < 8) ? y : 23 - y;             // complementary pairing
  const int b = bh >> 4, h = bh & 15;
  const int tid = threadIdx.x, w = tid >> 6, lane = tid & 63;
  const int l31 = lane & 31, hi = lane >> 5;
  const int k7 = l31 & 7, v15 = l31 & 15;
  const int nI = t + 1;

  const u16* Qb = Qo + (size_t)bh * SEQ * HD;
  const u16* Kb = Ko + (size_t)bh * SEQ * HD;
  const u16* Vb = Vo + (size_t)bh * HD * SEQ;

  const int kl = lane >> 3, kc = lane & 7;         // K staging lane decomp
  const int vl = lane >> 4, vc = lane & 15;        // V staging lane decomp
  const int mq = w * 32 + l31;                     // lane's q row within tile

  // Q B-operand frags [16d x 32q]: lane(q=l31,hi): d = ks*16 + hi*8 .. +8
  bf8 bq[4];
  #pragma unroll
  for (int ks = 0; ks < 4; ks++)
    bq[ks] = *(const bf8*)(Qb + (size_t)(t * 128 + w * 32 + l31) * HD + ks * 16 + hi * 8);

  f16v o0, o1, zf;
  #pragma unroll
  for (int i = 0; i < 16; i++) { o0[i] = 0.f; o1[i] = 0.f; zf[i] = 0.f; }
  float lsum = 0.f;

  const u16* kg = Kb + (size_t)(w * 32 + kl) * HD + ((kc ^ kl) * 8);
  const u16* vg[4];
  u16* ldsK[4];
  u16* ldsV[4];
  #pragma unroll
  for (int i = 0; i < 4; i++) {
    const int vr = w * 16 + i * 4;
    const int f = (i * 4 + vl) & 15;
    vg[i] = Vb + (size_t)(vr + vl) * SEQ + ((vc ^ f) * 8);
    ldsK[i] = &Ks[(w * 32 + i * 8) * 64];
    ldsV[i] = &Vs[vr * 128];
  }

  #pragma unroll
  for (int i = 0; i < 4; i++) {
    async16(kg + i * 512, ldsK[i]);
    async16(vg[i], ldsV[i]);
  }
  kg += 128 * HD;
  #pragma unroll
  for (int i = 0; i < 4; i++) vg[i] += 128;

  for (int it = 0; it < nI; ++it) {
    const int cb = (it & 1) * 8192;
    __syncthreads();
    if (it + 1 < nI) {
      const int nb = 8192 - cb;
      #pragma unroll
      for (int i = 0; i < 4; i++) {
        async16(kg + i * 512, ldsK[i] + nb);
        async16(vg[i], ldsV[i] + nb);
      }
      kg += 128 * HD;
      #pragma unroll
      for (int i = 0; i < 4; i++) vg[i] += 128;
    }
    const bool domask = (it == nI - 1);

    #pragma unroll
    for (int mf = 0; mf < 4; mf++) {
      // ---- QK^T: S^T[32k x 32q], accumulate over 4 k-steps of d ----
      f16v s;
      __builtin_amdgcn_s_setprio(1);
      {
        bf8 ak = *(const bf8*)&Ks[cb + mf * 2048 + l31 * 64 + ((hi ^ k7) * 8)];
        s = MFMA32(ak, bq[0], zf);
      }
      #pragma unroll
      for (int ks = 1; ks < 4; ks++) {
        bf8 ak = *(const bf8*)&Ks[cb + mf * 2048 + l31 * 64 + (((2 * ks + hi) ^ k7) * 8)];
        s = MFMA32(ak, bq[ks], s);
      }
      __builtin_amdgcn_s_setprio(0);

      // ---- exp2 + mask + running row-sum (q = l31) ----
      unsigned pu[16];
      #pragma unroll
      for (int r = 0; r < 16; r++) {
        float pv = EXP2(s[r]);
        if (domask) {
          const int kt = mf * 32 + (r & 3) + 8 * (r >> 2) + 4 * hi;
          pv = (kt <= mq) ? pv : 0.f;
        }
        lsum += pv;
        pu[r] = __float_as_uint(pv);
      }
      // ---- pack pairs to bf16, half-wave swap -> PV A-operand frags ----
      unsigned a0 = PKHI(pu[1],  pu[0]),  a1 = PKHI(pu[3],  pu[2]);
      unsigned a2 = PKHI(pu[5],  pu[4]),  a3 = PKHI(pu[7],  pu[6]);
      unsigned a4 = PKHI(pu[9],  pu[8]),  a5 = PKHI(pu[11], pu[10]);
      unsigned a6 = PKHI(pu[13], pu[12]), a7 = PKHI(pu[15], pu[14]);
      asm("v_permlane32_swap_b32 %0, %1" : "+v"(a0), "+v"(a2));
      asm("v_permlane32_swap_b32 %0, %1" : "+v"(a1), "+v"(a3));
      asm("v_permlane32_swap_b32 %0, %1" : "+v"(a4), "+v"(a6));
      asm("v_permlane32_swap_b32 %0, %1" : "+v"(a5), "+v"(a7));
      bf8 pf0, pf1;
      ((unsigned*)&pf0)[0] = a0; ((unsigned*)&pf0)[1] = a1;
      ((unsigned*)&pf0)[2] = a2; ((unsigned*)&pf0)[3] = a3;
      ((unsigned*)&pf1)[0] = a4; ((unsigned*)&pf1)[1] = a5;
      ((unsigned*)&pf1)[2] = a6; ((unsigned*)&pf1)[3] = a7;

      // ---- PV: O[q][d] += P^T-frag x V^T-frag, k-slots 2mf, 2mf+1 ----
      __builtin_amdgcn_s_setprio(1);
      {
        const int c0 = ((4 * mf + hi) ^ v15) * 8;
        bf8 vf0 = *(const bf8*)&Vs[cb + l31 * 128 + c0];
        bf8 vf1 = *(const bf8*)&Vs[cb + 4096 + l31 * 128 + c0];
        o0 = MFMA32(pf0, vf0, o0);
        o1 = MFMA32(pf0, vf1, o1);
      }
      {
        const int c1 = ((4 * mf + 2 + hi) ^ v15) * 8;
        bf8 vf0 = *(const bf8*)&Vs[cb + l31 * 128 + c1];
        bf8 vf1 = *(const bf8*)&Vs[cb + 4096 + l31 * 128 + c1];
        o0 = MFMA32(pf1, vf0, o0);
        o1 = MFMA32(pf1, vf1, o1);
      }
      __builtin_amdgcn_s_setprio(0);
    }
  }

  // ---- epilogue: l across half-waves, broadcast via LDS, scaled store ----
  const float lt = lsum + __shfl_xor(lsum, 32, 64);
  if (hi == 0) Ls[w * 32 + l31] = lt;
  __syncthreads();

  float* op = out + ((size_t)(b * SEQ + t * 128 + w * 32)) * (NH * HD) + h * HD + l31;
  #pragma unroll
  for (int r = 0; r < 16; r++) {
    const int qr = (r & 3) + 8 * (r >> 2) + 4 * hi;
    const float linv = 1.0f / Ls[w * 32 + qr];
    op[(size_t)qr * (NH * HD)]      = o0[r] * linv;
    op[(size_t)qr * (NH * HD) + 32] = o1[r] * linv;
  }
}

extern "C" void kernel_launch(void* const* d_in, const int* in_sizes, int n_in,
                              void* d_out, int out_size, void* d_ws, size_t ws_size,
                              hipStream_t stream) {
  const float* x  = (const float*)d_in[0];
  const float* Wq = (const float*)d_in[1];
  const float* Wk = (const float*)d_in[2];
  const float* Wv = (const float*)d_in[3];
  float* out = (float*)d_out;

  u16* xb = (u16*)d_ws;
  u16* Wt = xb + (size_t)NB * SEQ * DI;
  u16* Qo = Wt + (size_t)3 * NH * HD * DI;
  u16* Ko = Qo + (size_t)NB * NH * SEQ * HD;
  u16* Vo = Ko + (size_t)NB * NH * SEQ * HD;

  prep_k<<<dim3(2048 + 768), 256, 0, stream>>>(x, Wq, Wk, Wv, xb, Wt);
  proj_k<<<dim3(32, 16), 256, 0, stream>>>(xb, Wt, Qo, Ko, Vo);
  attn_k<<<dim3(32, 16), 256, 0, stream>>>(Qo, Ko, Vo, out);
}